// Round 1
// baseline (186.214 us; speedup 1.0000x reference)
//
#include <hip/hip_runtime.h>
#include <hip/hip_bf16.h>

#define N_NODES 256
#define ENTRIES 27
#define ACTION 4096
#define BATCH 8192
#define SDIM 322

typedef unsigned short u16;
typedef u16 u16x4 __attribute__((ext_vector_type(4)));
typedef u16 u16x8 __attribute__((ext_vector_type(8)));
typedef __bf16 bf16x8 __attribute__((ext_vector_type(8)));
typedef float floatx4 __attribute__((ext_vector_type(4)));

__device__ __forceinline__ u16 f2bf(float f) {
    unsigned u = __builtin_bit_cast(unsigned, f);
    unsigned r = (u + 0x7FFFu + ((u >> 16) & 1u)) >> 16;   // RNE
    return (u16)r;
}

// ---------------------------------------------------------------------------
// Kernel 1: y[b,n] = tanh( sum_e state[b, idx[n,e]] * W[n,e] + bias[n] )
// Block = 256 threads (thread == node), handles 8 batch rows staged in LDS.
// ---------------------------------------------------------------------------
__global__ __launch_bounds__(256) void node_kernel(
    const float* __restrict__ state, const float* __restrict__ W,
    const float* __restrict__ bias, const int* __restrict__ idx,
    u16* __restrict__ y)
{
    __shared__ float srow[8 * SDIM];   // 10304 B
    const int n  = threadIdx.x;
    const int b0 = blockIdx.x * 8;

    for (int i = threadIdx.x; i < 8 * SDIM; i += 256) {
        int r = i / SDIM;
        int c = i - r * SDIM;
        srow[i] = state[(size_t)(b0 + r) * SDIM + c];
    }

    int   ix[ENTRIES];
    float w [ENTRIES];
#pragma unroll
    for (int e = 0; e < ENTRIES; e++) {
        ix[e] = idx[n * ENTRIES + e];
        w [e] = W  [n * ENTRIES + e];
    }
    const float bb = bias[n];
    __syncthreads();

#pragma unroll
    for (int r = 0; r < 8; r++) {
        const float* sp = &srow[r * SDIM];
        float s = bb;
#pragma unroll
        for (int e = 0; e < ENTRIES; e++) s += sp[ix[e]] * w[e];
        y[(size_t)(b0 + r) * N_NODES + n] = f2bf(tanhf(s));
    }
}

// ---------------------------------------------------------------------------
// Kernel 2: Wf f32 [4096,256] -> bf16 (same layout, K contiguous)
// ---------------------------------------------------------------------------
__global__ __launch_bounds__(256) void conv_kernel(
    const float* __restrict__ wf, u16* __restrict__ out)
{
    const int i0 = (blockIdx.x * 256 + threadIdx.x) * 4;
    floatx4 v = *(const floatx4*)(wf + i0);
    u16x4 r;
    r.x = f2bf(v.x); r.y = f2bf(v.y); r.z = f2bf(v.z); r.w = f2bf(v.w);
    *(u16x4*)(out + i0) = r;
}

// ---------------------------------------------------------------------------
// Kernel 3: out[m,a] = 500*sigmoid( sum_k y[m,k] * Wf[a,k] )
// M=8192, N=4096, K=256. 128x128 tile, BK=32, 4 waves each 64x64.
// mfma_f32_16x16x32_bf16; A: m=lane&15, k=(lane>>4)*8+j ; B: n=lane&15 same k;
// C/D: col=lane&15, row=(lane>>4)*4+reg.
// ---------------------------------------------------------------------------
__global__ __launch_bounds__(256) void gemm_kernel(
    const u16* __restrict__ Y, const u16* __restrict__ WF,
    float* __restrict__ out)
{
    __shared__ u16 As[128 * 32];
    __shared__ u16 Bs[128 * 32];

    const int bm   = blockIdx.x;        // 0..63  (M tiles)
    const int bn   = blockIdx.y;        // 0..31  (A tiles)
    const int tid  = threadIdx.x;
    const int lane = tid & 63;
    const int wave = tid >> 6;          // 0..3
    const int wm   = wave & 1;          // M-dir wave
    const int wn   = wave >> 1;         // N-dir wave

    const int l15  = lane & 15;
    const int koff = (lane >> 4) << 3;  // k-offset within BK

    floatx4 acc[4][4];
#pragma unroll
    for (int mi = 0; mi < 4; mi++)
#pragma unroll
        for (int ni = 0; ni < 4; ni++)
            acc[mi][ni] = (floatx4){0.f, 0.f, 0.f, 0.f};

    const size_t arow0 = (size_t)bm * 128;
    const size_t brow0 = (size_t)bn * 128;

    for (int kk = 0; kk < 256; kk += 32) {
        __syncthreads();
        // stage A and B tiles: 512 chunks of 8 bf16 each per tile
#pragma unroll
        for (int c = tid; c < 512; c += 256) {
            int row = c >> 2;
            int k8  = (c & 3) << 3;
            *(u16x8*)&As[c * 8] =
                *(const u16x8*)&Y [(arow0 + row) * 256 + kk + k8];
            *(u16x8*)&Bs[c * 8] =
                *(const u16x8*)&WF[(brow0 + row) * 256 + kk + k8];
        }
        __syncthreads();

        bf16x8 afrag[4], bfrag[4];
#pragma unroll
        for (int mi = 0; mi < 4; mi++)
            afrag[mi] = __builtin_bit_cast(bf16x8,
                *(const u16x8*)&As[((wm << 6) + (mi << 4) + l15) * 32 + koff]);
#pragma unroll
        for (int ni = 0; ni < 4; ni++)
            bfrag[ni] = __builtin_bit_cast(bf16x8,
                *(const u16x8*)&Bs[((wn << 6) + (ni << 4) + l15) * 32 + koff]);

#pragma unroll
        for (int mi = 0; mi < 4; mi++)
#pragma unroll
            for (int ni = 0; ni < 4; ni++)
                acc[mi][ni] = __builtin_amdgcn_mfma_f32_16x16x32_bf16(
                    afrag[mi], bfrag[ni], acc[mi][ni], 0, 0, 0);
    }

    // epilogue: 500 * sigmoid(x)
    const int r0 = (lane >> 4) << 2;
#pragma unroll
    for (int mi = 0; mi < 4; mi++) {
#pragma unroll
        for (int ni = 0; ni < 4; ni++) {
            const int row = bm * 128 + wm * 64 + mi * 16 + r0;
            const int col = bn * 128 + wn * 64 + ni * 16 + l15;
#pragma unroll
            for (int r = 0; r < 4; r++) {
                float v = acc[mi][ni][r];
                out[(size_t)(row + r) * ACTION + col] =
                    500.0f / (1.0f + __expf(-v));
            }
        }
    }
}

extern "C" void kernel_launch(void* const* d_in, const int* in_sizes, int n_in,
                              void* d_out, int out_size, void* d_ws, size_t ws_size,
                              hipStream_t stream) {
    const float* state = (const float*)d_in[0];
    const float* W     = (const float*)d_in[1];
    const float* b     = (const float*)d_in[2];
    const float* Wf    = (const float*)d_in[3];
    const int*   idx   = (const int*)  d_in[4];
    float* out = (float*)d_out;

    u16* y   = (u16*)d_ws;                      // 8192*256 bf16 = 4 MB
    u16* wfb = y + (size_t)BATCH * N_NODES;     // 4096*256 bf16 = 2 MB

    node_kernel<<<BATCH / 8, 256, 0, stream>>>(state, W, b, idx, y);
    conv_kernel<<<(ACTION * N_NODES / 4) / 256, 256, 0, stream>>>(Wf, wfb);
    gemm_kernel<<<dim3(BATCH / 128, ACTION / 128), 256, 0, stream>>>(y, wfb, out);
}